// Round 1
// baseline (236.763 us; speedup 1.0000x reference)
//
#include <hip/hip_runtime.h>
#include <stdint.h>

#define NSUP   50000
#define NSUPP  50048      // padded to multiple of 128
#define NQRY   2048
#define KD     512
#define EPSV   1e-8f

#define BM 128
#define BN 128
#define BK 64

typedef __attribute__((ext_vector_type(8))) short bf16x8;
typedef __attribute__((ext_vector_type(4))) float f32x4;

__device__ __forceinline__ unsigned short f2bf(float f) {
  unsigned int u = __float_as_uint(f);
  u += 0x7FFFu + ((u >> 16) & 1u);   // round-to-nearest-even
  return (unsigned short)(u >> 16);
}

// ---- prep: fused norms + f32->bf16 convert (+ zero pad rows) ----
// One wave per row; 4 waves per block. Rows [0,NSUPP) = support (pad rows
// NSUP..NSUPP zeroed), rows [NSUPP, NSUPP+NQRY) = query.
__global__ __launch_bounds__(256) void prep_kernel(
    const float* __restrict__ sup, const float* __restrict__ qry,
    unsigned short* __restrict__ s_bf, unsigned short* __restrict__ q_bf,
    float* __restrict__ sn, float* __restrict__ qn) {
  const int row  = blockIdx.x * 4 + (threadIdx.x >> 6);
  const int lane = threadIdx.x & 63;

  const float* src = nullptr;
  unsigned short* dst;
  float* nrm = nullptr;
  if (row < NSUPP) {
    dst = s_bf + (size_t)row * KD;
    if (row < NSUP) { src = sup + (size_t)row * KD; nrm = sn + row; }
  } else {
    const int r = row - NSUPP;
    dst = q_bf + (size_t)r * KD;
    src = qry + (size_t)r * KD;
    nrm = qn + r;
  }

  if (src == nullptr) {           // zero pad row
    bf16x8 z = {};
    *(bf16x8*)(dst + lane * 8) = z;
    return;
  }

  const float4 v0 = ((const float4*)src)[lane * 2 + 0];
  const float4 v1 = ((const float4*)src)[lane * 2 + 1];
  float ss = v0.x*v0.x + v0.y*v0.y + v0.z*v0.z + v0.w*v0.w
           + v1.x*v1.x + v1.y*v1.y + v1.z*v1.z + v1.w*v1.w;

  bf16x8 o;
  o[0]=(short)f2bf(v0.x); o[1]=(short)f2bf(v0.y);
  o[2]=(short)f2bf(v0.z); o[3]=(short)f2bf(v0.w);
  o[4]=(short)f2bf(v1.x); o[5]=(short)f2bf(v1.y);
  o[6]=(short)f2bf(v1.z); o[7]=(short)f2bf(v1.w);
  *(bf16x8*)(dst + lane * 8) = o;

  #pragma unroll
  for (int off = 32; off > 0; off >>= 1) ss += __shfl_down(ss, off);
  if (lane == 0) *nrm = sqrtf(ss);
}

// ---- GEMM: C[q][n] = dot(query[q], support[n]) * 1/max(qn*sn, eps) ----
// m97 structure: 128x128 tile, BK=64, 4 waves each owning a 64x64 quadrant
// (4x4 fragments of 16x16x32), global_load_lds width-16 staging.
__global__ __launch_bounds__(256, 2) void gemm_kernel(
    const unsigned short* __restrict__ A,   // q_bf  [NQRY][KD]
    const unsigned short* __restrict__ B,   // s_bf  [NSUPP][KD]
    const float* __restrict__ qn, const float* __restrict__ sn,
    float* __restrict__ out) {
  __shared__ __attribute__((aligned(16))) unsigned short At[BM][BK];
  __shared__ __attribute__((aligned(16))) unsigned short Bt[BN][BK];

  const int tid = threadIdx.x;
  const int w = tid >> 6, l = tid & 63;
  const int tm = blockIdx.y * BM;   // query tile base
  const int tn = blockIdx.x * BN;   // support tile base
  const int wr = w >> 1, wc = w & 1;

  f32x4 acc[4][4] = {};

  // staging: lane l covers row (l>>3) of an 8-row group, k-chunk (l&7)*8
  const int srow = l >> 3;
  const int scol = (l & 7) * 8;
  const unsigned short* gA = A + (size_t)(tm + srow) * KD + scol;
  const unsigned short* gB = B + (size_t)(tn + srow) * KD + scol;

  for (int k0 = 0; k0 < KD; k0 += BK) {
    #pragma unroll
    for (int i = 0; i < 4; ++i) {
      const int rbase = i * 32 + w * 8;   // wave-uniform 8-row slice
      __builtin_amdgcn_global_load_lds(
          (const __attribute__((address_space(1))) void*)(gA + (size_t)rbase * KD + k0),
          (__attribute__((address_space(3))) void*)&At[rbase][0], 16, 0, 0);
      __builtin_amdgcn_global_load_lds(
          (const __attribute__((address_space(1))) void*)(gB + (size_t)rbase * KD + k0),
          (__attribute__((address_space(3))) void*)&Bt[rbase][0], 16, 0, 0);
    }
    __syncthreads();

    #pragma unroll
    for (int kk = 0; kk < 2; ++kk) {
      const int kof = kk * 32 + (l >> 4) * 8;
      const int rof = l & 15;
      bf16x8 a[4], b[4];
      #pragma unroll
      for (int m = 0; m < 4; ++m)
        a[m] = *(const bf16x8*)&At[wr * 64 + m * 16 + rof][kof];
      #pragma unroll
      for (int n = 0; n < 4; ++n)
        b[n] = *(const bf16x8*)&Bt[wc * 64 + n * 16 + rof][kof];
      #pragma unroll
      for (int m = 0; m < 4; ++m)
        #pragma unroll
        for (int n = 0; n < 4; ++n)
          acc[m][n] = __builtin_amdgcn_mfma_f32_16x16x32_bf16(a[m], b[n], acc[m][n], 0, 0, 0);
    }
    __syncthreads();
  }

  // epilogue: D row=(l>>4)*4+r, col=(l&15)  [m89 layout]
  const int hi = l >> 4, lo = l & 15;
  #pragma unroll
  for (int m = 0; m < 4; ++m) {
    const int qb = tm + wr * 64 + m * 16 + hi * 4;
    const float q0 = qn[qb + 0], q1 = qn[qb + 1];
    const float q2 = qn[qb + 2], q3 = qn[qb + 3];
    #pragma unroll
    for (int n = 0; n < 4; ++n) {
      const int col = tn + wc * 64 + n * 16 + lo;
      if (col < NSUP) {
        const float s = sn[col];
        float* o = out + (size_t)qb * NSUP + col;
        o[0 * (size_t)NSUP] = acc[m][n][0] / fmaxf(q0 * s, EPSV);
        o[1 * (size_t)NSUP] = acc[m][n][1] / fmaxf(q1 * s, EPSV);
        o[2 * (size_t)NSUP] = acc[m][n][2] / fmaxf(q2 * s, EPSV);
        o[3 * (size_t)NSUP] = acc[m][n][3] / fmaxf(q3 * s, EPSV);
      }
    }
  }
}

extern "C" void kernel_launch(void* const* d_in, const int* in_sizes, int n_in,
                              void* d_out, int out_size, void* d_ws, size_t ws_size,
                              hipStream_t stream) {
  const float* sup = (const float*)d_in[0];   // [50000][512] f32
  const float* qry = (const float*)d_in[1];   // [2048][512] f32
  float* out = (float*)d_out;                 // [2048][50000] f32

  char* ws = (char*)d_ws;
  unsigned short* s_bf = (unsigned short*)(ws);
  unsigned short* q_bf = (unsigned short*)(ws + (size_t)NSUPP * KD * 2);
  float* sn = (float*)(ws + (size_t)NSUPP * KD * 2 + (size_t)NQRY * KD * 2);
  float* qn = (float*)((char*)sn + (size_t)NSUP * 4);
  // total ws use: 50048*512*2 + 2048*512*2 + 50000*4 + 2048*4 ≈ 53.6 MB

  prep_kernel<<<(NSUPP + NQRY) / 4, 256, 0, stream>>>(sup, qry, s_bf, q_bf, sn, qn);

  dim3 grid(NSUPP / BN, NQRY / BM);  // (391, 16)
  gemm_kernel<<<grid, 256, 0, stream>>>(q_bf, s_bf, qn, sn, out);
}